// Round 9
// baseline (587.823 us; speedup 1.0000x reference)
//
#include <hip/hip_runtime.h>
#include <hip/hip_bf16.h>

typedef __attribute__((ext_vector_type(8))) short short8;
typedef __attribute__((ext_vector_type(4))) float f32x4;

#define TSEQ 2048
#define DMODEL 1024
#define NH 16
#define HD 64

__device__ __forceinline__ ushort f2bf(float f) {
    union { float f; unsigned int u; } c; c.f = f;
    unsigned int u = c.u + 0x7fffu + ((c.u >> 16) & 1u);   // RNE
    return (ushort)(u >> 16);
}

__device__ __forceinline__ float silu_f(float y) {
    return y / (1.f + __expf(-y));
}

// DPP add-reduce helpers (ctrl must be constexpr -> template param).
template <int CTRL>
__device__ __forceinline__ float dpp_add(float x) {
    return x + __int_as_float(__builtin_amdgcn_update_dpp(
        0, __float_as_int(x), CTRL, 0xF, 0xF, true));
}
__device__ __forceinline__ float red16(float x) {
    x = dpp_add<0xB1>(x);    // quad_perm xor 1
    x = dpp_add<0x4E>(x);    // quad_perm xor 2
    x = dpp_add<0x141>(x);   // row_half_mirror
    x = dpp_add<0x140>(x);   // row_mirror
    return x;
}

// async global->LDS (LDS dest = wave-uniform base + lane*size)
__device__ __forceinline__ void gl_lds16(const float* g, float* l) {
    __builtin_amdgcn_global_load_lds(
        (__attribute__((address_space(1))) void*)g,
        (__attribute__((address_space(3))) void*)l, 16, 0, 0);
}
__device__ __forceinline__ void gl_lds4(const float* g, float* l) {
    __builtin_amdgcn_global_load_lds(
        (__attribute__((address_space(1))) void*)g,
        (__attribute__((address_space(3))) void*)l, 4, 0, 0);
}
__device__ __forceinline__ void gl_lds16u(const ushort* g, ushort* l) {
    __builtin_amdgcn_global_load_lds(
        (__attribute__((address_space(1))) void*)g,
        (__attribute__((address_space(3))) void*)l, 16, 0, 0);
}

// ---------------- convert x -> bf16 ----------------
__global__ void gdn_cvt_x(const float* __restrict__ x, ushort* __restrict__ xb) {
    int i = blockIdx.x * 256 + threadIdx.x;
    float4 v = ((const float4*)x)[i];
    ushort4 o;
    o.x = f2bf(v.x); o.y = f2bf(v.y); o.z = f2bf(v.z); o.w = f2bf(v.w);
    ((ushort4*)xb)[i] = o;
}

// ------------- transpose+convert weights: W[k][n] f32 -> wt[z][n][k] bf16 -------------
__global__ void gdn_cvt_w(const float* __restrict__ Wq, const float* __restrict__ Wk,
                          const float* __restrict__ Wv, const float* __restrict__ Wg,
                          const float* __restrict__ Wo, ushort* __restrict__ wt) {
    __shared__ float tile[32][33];
    int z = blockIdx.z;
    const float* W = (z == 0) ? Wq : (z == 1) ? Wk : (z == 2) ? Wv : (z == 3) ? Wg : Wo;
    int n0 = blockIdx.x * 32, k0 = blockIdx.y * 32;
    int tx = threadIdx.x, ty = threadIdx.y;           // (32, 8)
    #pragma unroll
    for (int j = 0; j < 32; j += 8)
        tile[ty + j][tx] = W[(size_t)(k0 + ty + j) * DMODEL + n0 + tx];
    __syncthreads();
    ushort* o = wt + (size_t)z * DMODEL * DMODEL;
    #pragma unroll
    for (int j = 0; j < 32; j += 8)
        o[(size_t)(n0 + ty + j) * DMODEL + k0 + tx] = f2bf(tile[tx][ty + j]);
}

// ---------------- betaT[(b*NH+h)*TSEQ + t] = sigmoid(x @ Wb) ----------------
__global__ void gdn_beta(const float* __restrict__ x, const float* __restrict__ Wb,
                         float* __restrict__ betaT) {
    __shared__ float xs[16][DMODEL];
    int tid = threadIdx.x;
    int m0 = blockIdx.x * 16;
    #pragma unroll
    for (int i = 0; i < 16; i++) {
        int idx = i * 256 + tid;
        int row = idx >> 8, c4 = idx & 255;
        *(float4*)&xs[row][c4 * 4] =
            *(const float4*)&x[(size_t)(m0 + row) * DMODEL + c4 * 4];
    }
    __syncthreads();
    int h = tid & 15, mi = tid >> 4;
    float acc = 0.f;
    for (int k = 0; k < DMODEL; ++k)
        acc += xs[mi][k] * Wb[k * NH + h];
    int m = m0 + mi;
    int b = m >> 11, t = m & (TSEQ - 1);
    betaT[((b * NH + h) << 11) + t] = 1.f / (1.f + __expf(-acc));
}

// ---------------- qkT[(b*NH+h)*TSEQ + t] = dot(q[b,t,h,:], k[b,t,h,:]) ----------------
__global__ void gdn_qk(const float* __restrict__ qn, const float* __restrict__ kn,
                       float* __restrict__ qkT) {
    int m = blockIdx.x;
    int tid = threadIdx.x;
    int h = tid >> 4, part = tid & 15;
    size_t off = (size_t)m * 1024 + h * 64 + part * 4;
    float4 qv = *(const float4*)&qn[off];
    float4 kv = *(const float4*)&kn[off];
    float d = qv.x * kv.x + qv.y * kv.y + qv.z * kv.z + qv.w * kv.w;
    d += __shfl_xor(d, 1);
    d += __shfl_xor(d, 2);
    d += __shfl_xor(d, 4);
    d += __shfl_xor(d, 8);
    if (part == 0) {
        int b = m >> 11, t = m & (TSEQ - 1);
        qkT[((b * NH + h) << 11) + t] = d;
    }
}

// ---------------- bf16 MFMA GEMM (m97-style global_load_lds staging) ----------------
// out[M][ldOut] = A[M][1024] * Bt[N][1024]^T ; LDS [128][32] unpadded.
__global__ __launch_bounds__(256) void gdn_gemm(const ushort* __restrict__ A,
                                                const ushort* __restrict__ Bt,
                                                float* __restrict__ outF,
                                                int ldOut) {
    __shared__ ushort As[128 * 32];
    __shared__ ushort Bs[128 * 32];
    int tid = threadIdx.x;
    int lane = tid & 63, wid = tid >> 6;
    int wm = wid & 1, wn = wid >> 1;
    int l15 = lane & 15, quad = lane >> 4;
    int bm = blockIdx.x, bn = blockIdx.y;
    const int K = DMODEL;

    // staging: lane covers row wid*16 + lane/4 (+64 for second issue), 8 ushorts at (lane&3)*8
    const ushort* gA = A + (size_t)(bm * 128 + wid * 16 + (lane >> 2)) * K + (lane & 3) * 8;
    const ushort* gB = Bt + (size_t)(bn * 128 + wid * 16 + (lane >> 2)) * K + (lane & 3) * 8;
    ushort* lA = &As[(wid * 16) * 32];
    ushort* lB = &Bs[(wid * 16) * 32];

    f32x4 acc[4][4];
    #pragma unroll
    for (int i = 0; i < 4; i++)
        #pragma unroll
        for (int j = 0; j < 4; j++)
            acc[i][j] = (f32x4){0.f, 0.f, 0.f, 0.f};

    for (int kt = 0; kt < K; kt += 32) {
        __syncthreads();
        gl_lds16u(gA + kt, lA);
        gl_lds16u(gA + kt + (size_t)64 * K, lA + 64 * 32);
        gl_lds16u(gB + kt, lB);
        gl_lds16u(gB + kt + (size_t)64 * K, lB + 64 * 32);
        __syncthreads();
        short8 af[4], bf[4];
        #pragma unroll
        for (int i = 0; i < 4; i++) {
            af[i] = *(const short8*)&As[(wm * 64 + i * 16 + l15) * 32 + quad * 8];
            bf[i] = *(const short8*)&Bs[(wn * 64 + i * 16 + l15) * 32 + quad * 8];
        }
        #pragma unroll
        for (int mt = 0; mt < 4; mt++)
            #pragma unroll
            for (int nt = 0; nt < 4; nt++)
                acc[mt][nt] = __builtin_amdgcn_mfma_f32_16x16x32_bf16(
                    af[mt], bf[nt], acc[mt][nt], 0, 0, 0);
    }

    #pragma unroll
    for (int mt = 0; mt < 4; mt++)
        #pragma unroll
        for (int nt = 0; nt < 4; nt++)
            #pragma unroll
            for (int r = 0; r < 4; r++) {
                int row = bm * 128 + wm * 64 + mt * 16 + quad * 4 + r;
                int col = bn * 128 + wn * 64 + nt * 16 + l15;
                outF[(size_t)row * ldOut + col] = acc[mt][nt][r];
            }
}

// ---------------- causal depthwise conv(k=4) + silu (+ l2norm for q/k, q/=8) ----------------
__global__ void gdn_conv(const float* __restrict__ pre,
                         const float* __restrict__ cqw, const float* __restrict__ cqb,
                         const float* __restrict__ ckw, const float* __restrict__ ckb,
                         const float* __restrict__ cvw, const float* __restrict__ cvb,
                         float* __restrict__ qn, float* __restrict__ kn, float* __restrict__ vn) {
    int m = blockIdx.x;
    int which = blockIdx.y;        // 0:q 1:k 2:v
    int t = m & (TSEQ - 1);
    const float* cw = (which == 0) ? cqw : (which == 1) ? ckw : cvw;
    const float* cb = (which == 0) ? cqb : (which == 1) ? ckb : cvb;
    float* dst = (which == 0) ? qn : (which == 1) ? kn : vn;
    int c = threadIdx.x * 4;

    float w[4][4];
    #pragma unroll
    for (int i = 0; i < 4; i++) {
        float4 t4 = ((const float4*)cw)[c + i];
        w[i][0] = t4.x; w[i][1] = t4.y; w[i][2] = t4.z; w[i][3] = t4.w;
    }
    float4 bias = ((const float4*)cb)[threadIdx.x];
    float y[4] = {bias.x, bias.y, bias.z, bias.w};

    const float* src = pre + (size_t)m * 4096 + which * 1024 + c;
    #pragma unroll
    for (int j = 0; j < 4; j++) {
        int tt = t - 3 + j;
        if (tt >= 0) {
            float4 xv = *(const float4*)(src + (long)(j - 3) * 4096);
            y[0] += xv.x * w[0][j];
            y[1] += xv.y * w[1][j];
            y[2] += xv.z * w[2][j];
            y[3] += xv.w * w[3][j];
        }
    }
    #pragma unroll
    for (int i = 0; i < 4; i++) y[i] = silu_f(y[i]);

    if (which < 2) {
        float ss = y[0]*y[0] + y[1]*y[1] + y[2]*y[2] + y[3]*y[3];
        ss += __shfl_xor(ss, 1);
        ss += __shfl_xor(ss, 2);
        ss += __shfl_xor(ss, 4);
        ss += __shfl_xor(ss, 8);
        float sc = rsqrtf(ss + 1e-6f);
        if (which == 0) sc *= 0.125f;
        #pragma unroll
        for (int i = 0; i < 4; i++) y[i] *= sc;
    }
    float4 o; o.x = y[0]; o.y = y[1]; o.z = y[2]; o.w = y[3];
    ((float4*)(dst + (size_t)m * 1024))[threadIdx.x] = o;
}

// ---------------- delta-rule recurrence ----------------
// 512 blocks: blk = cg*32 + (b*16 + h)  [cg in HIGH bits -> all 16 cg-blocks of one
// (b,h) land on the same XCD for L2 reuse of k/q].
// lane = col*16 + rq: col = lane>>4 (global col cg*4+col), rq = lane&15 owns rows
// rq*4..rq*4+3. Chain shortened via q.S_new = q.S_old + (q.k)*err with q.k precomputed.
#define RC 32
__global__ __launch_bounds__(64) void gdn_recur(const float* __restrict__ qn,
                                                const float* __restrict__ kn,
                                                const float* __restrict__ vn,
                                                const float* __restrict__ betaT,
                                                const float* __restrict__ qkT,
                                                float* __restrict__ otmp2) {
    __shared__ float k_lds[2][RC][64];
    __shared__ float q_lds[2][RC][64];
    __shared__ float v_lds[2][RC][4];
    __shared__ float o_lds[RC * 4];
    __shared__ float beta_lds[TSEQ];
    __shared__ float qk_lds[TSEQ];

    int blk = blockIdx.x;
    int cg = blk >> 5;
    int s = blk & 31;
    int b = s >> 4;
    int h = s & 15;
    int lane = threadIdx.x;
    int col = lane >> 4;
    int rq4 = (lane & 15) * 4;

    float S[4] = {0.f, 0.f, 0.f, 0.f};

    size_t base0 = (size_t)b * TSEQ * 1024 + h * 64;

    const float* kg = kn + base0 + (size_t)(lane >> 4) * 1024 + (lane & 15) * 4;
    const float* qg = qn + base0 + (size_t)(lane >> 4) * 1024 + (lane & 15) * 4;
    const float* vg = vn + base0 + (size_t)(lane >> 2) * 1024 + cg * 4 + (lane & 3);

    // preload betas and qk dots for this (b,h)
    {
        const float* bsrc = betaT + ((size_t)(b * NH + h) << 11);
        const float* qsrc = qkT + ((size_t)(b * NH + h) << 11);
        #pragma unroll
        for (int i = 0; i < TSEQ / 64; ++i) {
            beta_lds[i * 64 + lane] = bsrc[i * 64 + lane];
            qk_lds[i * 64 + lane] = qsrc[i * 64 + lane];
        }
    }

    #define ISSUE_CHUNK(T0, BUF)                                             \
        {                                                                    \
            _Pragma("unroll")                                                \
            for (int i = 0; i < RC / 4; i++) {                               \
                gl_lds16(kg + (size_t)((T0) + i * 4) * 1024,                 \
                         &k_lds[BUF][i * 4][0]);                             \
                gl_lds16(qg + (size_t)((T0) + i * 4) * 1024,                 \
                         &q_lds[BUF][i * 4][0]);                             \
            }                                                                \
            _Pragma("unroll")                                                \
            for (int j = 0; j < RC / 16; j++)                                \
                gl_lds4(vg + (size_t)((T0) + j * 16) * 1024,                 \
                        &v_lds[BUF][j * 16][0]);                             \
        }

    ISSUE_CHUNK(0, 0);
    __syncthreads();

    float* ob = otmp2 + (size_t)((b * NH + h) * 16 + cg) * (TSEQ * 4);

    for (int c = 0; c < TSEQ / RC; ++c) {
        if (c + 1 < TSEQ / RC) ISSUE_CHUNK((c + 1) * RC, (c + 1) & 1);

        const float* kb = &k_lds[c & 1][0][0];
        const float* qb = &q_lds[c & 1][0][0];
        const float* vb = &v_lds[c & 1][0][0];
        const float* bb = &beta_lds[c * RC];
        const float* qq = &qk_lds[c * RC];

        #pragma unroll
        for (int t = 0; t < RC; ++t) {
            float4 kf = *(const float4*)&kb[t * 64 + rq4];
            float4 qf = *(const float4*)&qb[t * 64 + rq4];
            float vv = vb[t * 4 + col];
            float bt = bb[t];
            float qkd = qq[t];

            // critical chain: p -> red16 -> err -> S update
            float p0 = kf.x * S[0];
            float p1 = kf.y * S[1];
            float p2 = kf.z * S[2];
            float p3 = kf.w * S[3];
            float pk = red16((p0 + p1) + (p2 + p3));
            // off-chain: qs = q . S_old
            float s0 = qf.x * S[0];
            float s1 = qf.y * S[1];
            float s2 = qf.z * S[2];
            float s3 = qf.w * S[3];
            float qs = red16((s0 + s1) + (s2 + s3));

            float err = (vv - pk) * bt;

            S[0] += kf.x * err;
            S[1] += kf.y * err;
            S[2] += kf.z * err;
            S[3] += kf.w * err;

            float pq = qs + qkd * err;   // q.S_new
            if ((lane & 15) == 0) o_lds[t * 4 + col] = pq;
        }
        __syncthreads();
        ob[c * (RC * 4) + lane] = o_lds[lane];
        ob[c * (RC * 4) + 64 + lane] = o_lds[64 + lane];
    }
    #undef ISSUE_CHUNK
}

// ---------------- RMSNorm * nw * silu(gate) -> bf16 ----------------
__global__ void gdn_fuse(const float* __restrict__ otmp2, const float* __restrict__ pre,
                         const float* __restrict__ nw, ushort* __restrict__ ofused) {
    int m = blockIdx.x;
    int b = m >> 11, t = m & (TSEQ - 1);
    int tid = threadIdx.x;
    float4 o = ((const float4*)otmp2)[((size_t)((b * NH + (tid >> 4)) * 16 + (tid & 15))) * TSEQ + t];
    float ss = o.x*o.x + o.y*o.y + o.z*o.z + o.w*o.w;
    ss += __shfl_xor(ss, 1);
    ss += __shfl_xor(ss, 2);
    ss += __shfl_xor(ss, 4);
    ss += __shfl_xor(ss, 8);
    float r = rsqrtf(ss * (1.f / 64.f) + 1e-5f);
    float4 nwv = ((const float4*)nw)[tid & 15];
    float4 g = ((const float4*)(pre + (size_t)m * 4096 + 3072))[tid];
    ushort4 out;
    out.x = f2bf(o.x * r * nwv.x * silu_f(g.x));
    out.y = f2bf(o.y * r * nwv.y * silu_f(g.y));
    out.z = f2bf(o.z * r * nwv.z * silu_f(g.z));
    out.w = f2bf(o.w * r * nwv.w * silu_f(g.w));
    ((ushort4*)ofused)[m * 256 + tid] = out;
}

extern "C" void kernel_launch(void* const* d_in, const int* in_sizes, int n_in,
                              void* d_out, int out_size, void* d_ws, size_t ws_size,
                              hipStream_t stream) {
    const float* x    = (const float*)d_in[0];
    const float* Wq   = (const float*)d_in[1];
    const float* Wk   = (const float*)d_in[2];
    const float* Wv   = (const float*)d_in[3];
    const float* Wo   = (const float*)d_in[4];
    const float* Wg   = (const float*)d_in[5];
    const float* Wb   = (const float*)d_in[6];
    const float* cq_w = (const float*)d_in[7];
    const float* cq_b = (const float*)d_in[8];
    const float* ck_w = (const float*)d_in[9];
    const float* ck_b = (const float*)d_in[10];
    const float* cv_w = (const float*)d_in[11];
    const float* cv_b = (const float*)d_in[12];
    const float* nw   = (const float*)d_in[13];

    char* ws = (char*)d_ws;
    ushort* xb     = (ushort*)(ws);                       // 8 MB
    ushort* wt     = (ushort*)(ws + 8388608);             // 10 MB
    float*  pre    = (float*)(ws + 18874368);             // 64 MB
    float*  qn     = (float*)(ws + 85983232);             // 16 MB
    float*  kn     = (float*)(ws + 102760448);            // 16 MB
    float*  vn     = (float*)(ws + 119537664);            // 16 MB
    float*  betaT  = (float*)(ws + 136314880);            // 256 KB
    float*  otmp2  = (float*)(ws + 136577024);            // 16 MB
    ushort* ofused = (ushort*)(ws + 153354240);           // 8 MB
    float*  qkT    = (float*)(ws + 161742848);            // 256 KB (total ~162 MB)

    // 1. x -> bf16
    gdn_cvt_x<<<4096, 256, 0, stream>>>(x, xb);
    // 2. transpose+convert 5 weights
    gdn_cvt_w<<<dim3(32, 32, 5), dim3(32, 8), 0, stream>>>(Wq, Wk, Wv, Wg, Wo, wt);
    // 3. betaT
    gdn_beta<<<256, 256, 0, stream>>>(x, Wb, betaT);
    // 4. fused q/k/v/g pre-activation GEMM
    gdn_gemm<<<dim3(32, 32), 256, 0, stream>>>(xb, wt, pre, 4096);
    // 5. conv + silu (+ l2norm)
    gdn_conv<<<dim3(4096, 3), 256, 0, stream>>>(pre, cq_w, cq_b, ck_w, ck_b, cv_w, cv_b,
                                                qn, kn, vn);
    // 5b. q.k dots
    gdn_qk<<<4096, 256, 0, stream>>>(qn, kn, qkT);
    // 6. delta-rule recurrence
    gdn_recur<<<512, 64, 0, stream>>>(qn, kn, vn, betaT, qkT, otmp2);
    // 7. RMSNorm * nw * silu(gate) -> bf16
    gdn_fuse<<<4096, 256, 0, stream>>>(otmp2, pre, nw, ofused);
    // 8. final GEMM -> d_out (fp32 output)
    gdn_gemm<<<dim3(32, 8), 256, 0, stream>>>(ofused, wt + 4 * 1024 * 1024,
                                              (float*)d_out, 1024);
}

// Round 10
// 545.703 us; speedup vs baseline: 1.0772x; 1.0772x over previous
//
#include <hip/hip_runtime.h>
#include <hip/hip_bf16.h>

typedef __attribute__((ext_vector_type(8))) short short8;
typedef __attribute__((ext_vector_type(4))) float f32x4;

#define TSEQ 2048
#define DMODEL 1024
#define NH 16
#define HD 64

__device__ __forceinline__ ushort f2bf(float f) {
    union { float f; unsigned int u; } c; c.f = f;
    unsigned int u = c.u + 0x7fffu + ((c.u >> 16) & 1u);   // RNE
    return (ushort)(u >> 16);
}

__device__ __forceinline__ float silu_f(float y) {
    return y / (1.f + __expf(-y));
}

// DPP add-reduce helpers (ctrl constexpr via template param).
template <int CTRL>
__device__ __forceinline__ float dpp_add(float x) {
    return x + __int_as_float(__builtin_amdgcn_update_dpp(
        0, __float_as_int(x), CTRL, 0xF, 0xF, true));
}
// Sum over each 32-lane half (butterfly: mirrors valid due to sub-uniformity;
// final xor16 exact via ds_swizzle BitMode).
__device__ __forceinline__ float red32(float x) {
    x = dpp_add<0xB1>(x);    // quad_perm xor1
    x = dpp_add<0x4E>(x);    // quad_perm xor2
    x = dpp_add<0x141>(x);   // row_half_mirror (== xor4 given uniform-in-4)
    x = dpp_add<0x140>(x);   // row_mirror      (== xor8 given uniform-in-8)
    x += __int_as_float(__builtin_amdgcn_ds_swizzle(__float_as_int(x), 0x401F)); // xor16
    return x;
}

// async global->LDS (LDS dest = wave-uniform base + lane*size)
__device__ __forceinline__ void gl_lds16(const float* g, float* l) {
    __builtin_amdgcn_global_load_lds(
        (__attribute__((address_space(1))) void*)g,
        (__attribute__((address_space(3))) void*)l, 16, 0, 0);
}
__device__ __forceinline__ void gl_lds4(const float* g, float* l) {
    __builtin_amdgcn_global_load_lds(
        (__attribute__((address_space(1))) void*)g,
        (__attribute__((address_space(3))) void*)l, 4, 0, 0);
}

// ---------------- convert x -> bf16 ----------------
__global__ void gdn_cvt_x(const float* __restrict__ x, ushort* __restrict__ xb) {
    int i = blockIdx.x * 256 + threadIdx.x;
    float4 v = ((const float4*)x)[i];
    ushort4 o;
    o.x = f2bf(v.x); o.y = f2bf(v.y); o.z = f2bf(v.z); o.w = f2bf(v.w);
    ((ushort4*)xb)[i] = o;
}

// ------------- transpose+convert weights: W[k][n] f32 -> wt[z][n][k] bf16 -------------
__global__ void gdn_cvt_w(const float* __restrict__ Wq, const float* __restrict__ Wk,
                          const float* __restrict__ Wv, const float* __restrict__ Wg,
                          const float* __restrict__ Wo, ushort* __restrict__ wt) {
    __shared__ float tile[32][33];
    int z = blockIdx.z;
    const float* W = (z == 0) ? Wq : (z == 1) ? Wk : (z == 2) ? Wv : (z == 3) ? Wg : Wo;
    int n0 = blockIdx.x * 32, k0 = blockIdx.y * 32;
    int tx = threadIdx.x, ty = threadIdx.y;           // (32, 8)
    #pragma unroll
    for (int j = 0; j < 32; j += 8)
        tile[ty + j][tx] = W[(size_t)(k0 + ty + j) * DMODEL + n0 + tx];
    __syncthreads();
    ushort* o = wt + (size_t)z * DMODEL * DMODEL;
    #pragma unroll
    for (int j = 0; j < 32; j += 8)
        o[(size_t)(n0 + ty + j) * DMODEL + k0 + tx] = f2bf(tile[tx][ty + j]);
}

// ---------------- betaT[(b*NH+h)*TSEQ + t] = sigmoid(x @ Wb) ----------------
__global__ void gdn_beta(const float* __restrict__ x, const float* __restrict__ Wb,
                         float* __restrict__ betaT) {
    __shared__ float xs[16][DMODEL];
    int tid = threadIdx.x;
    int m0 = blockIdx.x * 16;
    #pragma unroll
    for (int i = 0; i < 16; i++) {
        int idx = i * 256 + tid;
        int row = idx >> 8, c4 = idx & 255;
        *(float4*)&xs[row][c4 * 4] =
            *(const float4*)&x[(size_t)(m0 + row) * DMODEL + c4 * 4];
    }
    __syncthreads();
    int h = tid & 15, mi = tid >> 4;
    float acc = 0.f;
    for (int k = 0; k < DMODEL; ++k)
        acc += xs[mi][k] * Wb[k * NH + h];
    int m = m0 + mi;
    int b = m >> 11, t = m & (TSEQ - 1);
    betaT[((b * NH + h) << 11) + t] = 1.f / (1.f + __expf(-acc));
}

// ---------------- qkT[(b*NH+h)*TSEQ + t] = dot(q[b,t,h,:], k[b,t,h,:]) ----------------
__global__ void gdn_qk(const float* __restrict__ qn, const float* __restrict__ kn,
                       float* __restrict__ qkT) {
    int m = blockIdx.x;
    int tid = threadIdx.x;
    int h = tid >> 4, part = tid & 15;
    size_t off = (size_t)m * 1024 + h * 64 + part * 4;
    float4 qv = *(const float4*)&qn[off];
    float4 kv = *(const float4*)&kn[off];
    float d = qv.x * kv.x + qv.y * kv.y + qv.z * kv.z + qv.w * kv.w;
    d += __shfl_xor(d, 1);
    d += __shfl_xor(d, 2);
    d += __shfl_xor(d, 4);
    d += __shfl_xor(d, 8);
    if (part == 0) {
        int b = m >> 11, t = m & (TSEQ - 1);
        qkT[((b * NH + h) << 11) + t] = d;
    }
}

// ---------------- bf16 MFMA GEMM (round-8 proven version) ----------------
#define LDT 40
__global__ __launch_bounds__(256) void gdn_gemm(const ushort* __restrict__ A,
                                                const ushort* __restrict__ Bt,
                                                float* __restrict__ outF,
                                                int ldOut) {
    __shared__ ushort As[128 * LDT];
    __shared__ ushort Bs[128 * LDT];
    int tid = threadIdx.x;
    int lane = tid & 63, wid = tid >> 6;
    int wm = wid & 1, wn = wid >> 1;
    int l15 = lane & 15, quad = lane >> 4;
    int bm = blockIdx.x, bn = blockIdx.y;
    const int K = DMODEL;

    f32x4 acc[4][4];
    #pragma unroll
    for (int i = 0; i < 4; i++)
        #pragma unroll
        for (int j = 0; j < 4; j++)
            acc[i][j] = (f32x4){0.f, 0.f, 0.f, 0.f};

    for (int kt = 0; kt < K; kt += 32) {
        __syncthreads();
        #pragma unroll
        for (int i = 0; i < 2; i++) {
            int ch = tid * 2 + i;
            int row = ch >> 2, q = ch & 3;
            uint4 av = ((const uint4*)A)[((bm * 128 + row) * K + kt) / 8 + q];
            *(uint4*)&As[row * LDT + q * 8] = av;
            uint4 bv = ((const uint4*)Bt)[((bn * 128 + row) * K + kt) / 8 + q];
            *(uint4*)&Bs[row * LDT + q * 8] = bv;
        }
        __syncthreads();
        short8 af[4], bf[4];
        #pragma unroll
        for (int i = 0; i < 4; i++) {
            af[i] = *(const short8*)&As[(wm * 64 + i * 16 + l15) * LDT + quad * 8];
            bf[i] = *(const short8*)&Bs[(wn * 64 + i * 16 + l15) * LDT + quad * 8];
        }
        #pragma unroll
        for (int mt = 0; mt < 4; mt++)
            #pragma unroll
            for (int nt = 0; nt < 4; nt++)
                acc[mt][nt] = __builtin_amdgcn_mfma_f32_16x16x32_bf16(
                    af[mt], bf[nt], acc[mt][nt], 0, 0, 0);
    }

    #pragma unroll
    for (int mt = 0; mt < 4; mt++)
        #pragma unroll
        for (int nt = 0; nt < 4; nt++)
            #pragma unroll
            for (int r = 0; r < 4; r++) {
                int row = bm * 128 + wm * 64 + mt * 16 + quad * 4 + r;
                int col = bn * 128 + wn * 64 + nt * 16 + l15;
                outF[(size_t)row * ldOut + col] = acc[mt][nt][r];
            }
}

// ---------------- causal depthwise conv(k=4) + silu (+ l2norm for q/k, q/=8) ----------------
__global__ void gdn_conv(const float* __restrict__ pre,
                         const float* __restrict__ cqw, const float* __restrict__ cqb,
                         const float* __restrict__ ckw, const float* __restrict__ ckb,
                         const float* __restrict__ cvw, const float* __restrict__ cvb,
                         float* __restrict__ qn, float* __restrict__ kn, float* __restrict__ vn) {
    int m = blockIdx.x;
    int which = blockIdx.y;        // 0:q 1:k 2:v
    int t = m & (TSEQ - 1);
    const float* cw = (which == 0) ? cqw : (which == 1) ? ckw : cvw;
    const float* cb = (which == 0) ? cqb : (which == 1) ? ckb : cvb;
    float* dst = (which == 0) ? qn : (which == 1) ? kn : vn;
    int c = threadIdx.x * 4;

    float w[4][4];
    #pragma unroll
    for (int i = 0; i < 4; i++) {
        float4 t4 = ((const float4*)cw)[c + i];
        w[i][0] = t4.x; w[i][1] = t4.y; w[i][2] = t4.z; w[i][3] = t4.w;
    }
    float4 bias = ((const float4*)cb)[threadIdx.x];
    float y[4] = {bias.x, bias.y, bias.z, bias.w};

    const float* src = pre + (size_t)m * 4096 + which * 1024 + c;
    #pragma unroll
    for (int j = 0; j < 4; j++) {
        int tt = t - 3 + j;
        if (tt >= 0) {
            float4 xv = *(const float4*)(src + (long)(j - 3) * 4096);
            y[0] += xv.x * w[0][j];
            y[1] += xv.y * w[1][j];
            y[2] += xv.z * w[2][j];
            y[3] += xv.w * w[3][j];
        }
    }
    #pragma unroll
    for (int i = 0; i < 4; i++) y[i] = silu_f(y[i]);

    if (which < 2) {
        float ss = y[0]*y[0] + y[1]*y[1] + y[2]*y[2] + y[3]*y[3];
        ss += __shfl_xor(ss, 1);
        ss += __shfl_xor(ss, 2);
        ss += __shfl_xor(ss, 4);
        ss += __shfl_xor(ss, 8);
        float sc = rsqrtf(ss + 1e-6f);
        if (which == 0) sc *= 0.125f;
        #pragma unroll
        for (int i = 0; i < 4; i++) y[i] *= sc;
    }
    float4 o; o.x = y[0]; o.y = y[1]; o.z = y[2]; o.w = y[3];
    ((float4*)(dst + (size_t)m * 1024))[threadIdx.x] = o;
}

// ---------------- delta-rule recurrence ----------------
// 1024 blocks (1 wave each): blk = cp*32 + (b*16+h); cp = column pair 0..31
// [bh in LOW bits -> all 32 cp-blocks of one (b,h) on the same XCD].
// lane = half*32 + r: half selects column cp*2+half; lane owns dims r and r+32.
// Reduction = red32 over each 32-lane half. q.S_new = q.S_old + (q.k)*err.
// Output layout: otmp2[((b*NH+h)*32+cp)*TSEQ*2 + t*2 + half].
#define RC 32
__global__ __launch_bounds__(64) void gdn_recur(const float* __restrict__ qn,
                                                const float* __restrict__ kn,
                                                const float* __restrict__ vn,
                                                const float* __restrict__ betaT,
                                                const float* __restrict__ qkT,
                                                float* __restrict__ otmp2) {
    __shared__ float k_lds[2][RC][64];
    __shared__ float q_lds[2][RC][64];
    __shared__ float v_lds[2][RC][2];
    __shared__ float bq_lds[2][64];     // [0..31]=beta, [32..63]=qk for the chunk
    __shared__ float o_lds[RC][2];

    int blk = blockIdx.x;
    int cp = blk >> 5;
    int s = blk & 31;
    int b = s >> 4;
    int h = s & 15;
    int lane = threadIdx.x;
    int half = lane >> 5;
    int r = lane & 31;

    float S0 = 0.f, S1 = 0.f;

    size_t base0 = (size_t)b * TSEQ * 1024 + h * 64;

    // staging pointers (per-lane)
    const float* kg = kn + base0 + (size_t)(lane >> 4) * 1024 + (lane & 15) * 4;
    const float* qg = qn + base0 + (size_t)(lane >> 4) * 1024 + (lane & 15) * 4;
    const float* vg = vn + base0 + (size_t)(lane >> 1) * 1024 + cp * 2 + (lane & 1);
    const float* bqg = (lane < 32)
        ? betaT + ((size_t)(b * NH + h) << 11) + lane
        : qkT + ((size_t)(b * NH + h) << 11) + (lane - 32);

    #define ISSUE_CHUNK(T0, BUF)                                             \
        {                                                                    \
            _Pragma("unroll")                                                \
            for (int i = 0; i < 8; i++) {                                    \
                gl_lds16(kg + (size_t)((T0) + i * 4) * 1024,                 \
                         &k_lds[BUF][i * 4][0]);                             \
                gl_lds16(qg + (size_t)((T0) + i * 4) * 1024,                 \
                         &q_lds[BUF][i * 4][0]);                             \
            }                                                                \
            gl_lds4(vg + (size_t)(T0) * 1024, &v_lds[BUF][0][0]);            \
            gl_lds4(bqg + (T0), &bq_lds[BUF][0]);                            \
        }

    ISSUE_CHUNK(0, 0);
    __syncthreads();

    float* ob = otmp2 + (size_t)((b * NH + h) * 32 + cp) * (TSEQ * 2);

    for (int c = 0; c < TSEQ / RC; ++c) {
        if (c + 1 < TSEQ / RC) ISSUE_CHUNK((c + 1) * RC, (c + 1) & 1);

        const float* kb = &k_lds[c & 1][0][0];
        const float* qb = &q_lds[c & 1][0][0];
        const float* vb = &v_lds[c & 1][0][0];
        const float* bq = &bq_lds[c & 1][0];

        // register pipeline: preload step 0
        float kr0[2], kr1[2], qr0[2], qr1[2], vr[2], br[2], qkr[2];
        kr0[0] = kb[r]; kr1[0] = kb[32 + r];
        qr0[0] = qb[r]; qr1[0] = qb[32 + r];
        vr[0] = vb[half];
        br[0] = bq[0];
        qkr[0] = bq[32];

        #pragma unroll
        for (int t = 0; t < RC; ++t) {
            int cur = t & 1, nxt = cur ^ 1;
            if (t + 1 < RC) {
                kr0[nxt] = kb[(t + 1) * 64 + r];
                kr1[nxt] = kb[(t + 1) * 64 + 32 + r];
                qr0[nxt] = qb[(t + 1) * 64 + r];
                qr1[nxt] = qb[(t + 1) * 64 + 32 + r];
                vr[nxt] = vb[(t + 1) * 2 + half];
                br[nxt] = bq[t + 1];
                qkr[nxt] = bq[32 + t + 1];
            }
            float k0 = kr0[cur], k1 = kr1[cur];
            float q0 = qr0[cur], q1 = qr1[cur];
            float vv = vr[cur], bt = br[cur], qkd = qkr[cur];

            float pk = red32(k0 * S0 + k1 * S1);
            float qs = red32(q0 * S0 + q1 * S1);
            float err = (vv - pk) * bt;
            S0 += k0 * err;
            S1 += k1 * err;
            float pq = qs + qkd * err;
            if (r == 0) o_lds[t][half] = pq;
        }
        __syncthreads();
        ob[c * (RC * 2) + lane] = (&o_lds[0][0])[lane];
    }
    #undef ISSUE_CHUNK
}

// ---------------- RMSNorm * nw * silu(gate) -> bf16 ----------------
__global__ void gdn_fuse(const float* __restrict__ otmp2, const float* __restrict__ pre,
                         const float* __restrict__ nw, ushort* __restrict__ ofused) {
    int m = blockIdx.x;
    int b = m >> 11, t = m & (TSEQ - 1);
    int tid = threadIdx.x;
    int hh = tid >> 4;
    int cp0 = (tid & 15) * 2;
    const float* obase = otmp2 + (size_t)((b * NH + hh) * 32) * (TSEQ * 2);
    float2 lo = *(const float2*)&obase[(size_t)cp0 * (TSEQ * 2) + t * 2];
    float2 hi = *(const float2*)&obase[(size_t)(cp0 + 1) * (TSEQ * 2) + t * 2];
    float4 o; o.x = lo.x; o.y = lo.y; o.z = hi.x; o.w = hi.y;
    float ss = o.x*o.x + o.y*o.y + o.z*o.z + o.w*o.w;
    ss += __shfl_xor(ss, 1);
    ss += __shfl_xor(ss, 2);
    ss += __shfl_xor(ss, 4);
    ss += __shfl_xor(ss, 8);
    float r = rsqrtf(ss * (1.f / 64.f) + 1e-5f);
    float4 nwv = ((const float4*)nw)[tid & 15];
    float4 g = ((const float4*)(pre + (size_t)m * 4096 + 3072))[tid];
    ushort4 out;
    out.x = f2bf(o.x * r * nwv.x * silu_f(g.x));
    out.y = f2bf(o.y * r * nwv.y * silu_f(g.y));
    out.z = f2bf(o.z * r * nwv.z * silu_f(g.z));
    out.w = f2bf(o.w * r * nwv.w * silu_f(g.w));
    ((ushort4*)ofused)[m * 256 + tid] = out;
}

extern "C" void kernel_launch(void* const* d_in, const int* in_sizes, int n_in,
                              void* d_out, int out_size, void* d_ws, size_t ws_size,
                              hipStream_t stream) {
    const float* x    = (const float*)d_in[0];
    const float* Wq   = (const float*)d_in[1];
    const float* Wk   = (const float*)d_in[2];
    const float* Wv   = (const float*)d_in[3];
    const float* Wo   = (const float*)d_in[4];
    const float* Wg   = (const float*)d_in[5];
    const float* Wb   = (const float*)d_in[6];
    const float* cq_w = (const float*)d_in[7];
    const float* cq_b = (const float*)d_in[8];
    const float* ck_w = (const float*)d_in[9];
    const float* ck_b = (const float*)d_in[10];
    const float* cv_w = (const float*)d_in[11];
    const float* cv_b = (const float*)d_in[12];
    const float* nw   = (const float*)d_in[13];

    char* ws = (char*)d_ws;
    ushort* xb     = (ushort*)(ws);                       // 8 MB
    ushort* wt     = (ushort*)(ws + 8388608);             // 10 MB
    float*  pre    = (float*)(ws + 18874368);             // 64 MB
    float*  qn     = (float*)(ws + 85983232);             // 16 MB
    float*  kn     = (float*)(ws + 102760448);            // 16 MB
    float*  vn     = (float*)(ws + 119537664);            // 16 MB
    float*  betaT  = (float*)(ws + 136314880);            // 256 KB
    float*  otmp2  = (float*)(ws + 136577024);            // 16 MB
    ushort* ofused = (ushort*)(ws + 153354240);           // 8 MB
    float*  qkT    = (float*)(ws + 161742848);            // 256 KB

    // 1. x -> bf16
    gdn_cvt_x<<<4096, 256, 0, stream>>>(x, xb);
    // 2. transpose+convert 5 weights
    gdn_cvt_w<<<dim3(32, 32, 5), dim3(32, 8), 0, stream>>>(Wq, Wk, Wv, Wg, Wo, wt);
    // 3. betaT
    gdn_beta<<<256, 256, 0, stream>>>(x, Wb, betaT);
    // 4. fused q/k/v/g pre-activation GEMM
    gdn_gemm<<<dim3(32, 32), 256, 0, stream>>>(xb, wt, pre, 4096);
    // 5. conv + silu (+ l2norm)
    gdn_conv<<<dim3(4096, 3), 256, 0, stream>>>(pre, cq_w, cq_b, ck_w, ck_b, cv_w, cv_b,
                                                qn, kn, vn);
    // 5b. q.k dots
    gdn_qk<<<4096, 256, 0, stream>>>(qn, kn, qkT);
    // 6. delta-rule recurrence (1024 waves, 2 cols/wave, red32)
    gdn_recur<<<1024, 64, 0, stream>>>(qn, kn, vn, betaT, qkT, otmp2);
    // 7. RMSNorm * nw * silu(gate) -> bf16
    gdn_fuse<<<4096, 256, 0, stream>>>(otmp2, pre, nw, ofused);
    // 8. final GEMM -> d_out (fp32 output)
    gdn_gemm<<<dim3(32, 8), 256, 0, stream>>>(ofused, wt + 4 * 1024 * 1024,
                                              (float*)d_out, 1024);
}